// Round 9
// baseline (98.953 us; speedup 1.0000x reference)
//
#include <hip/hip_runtime.h>
#include <hip/hip_bf16.h>
#include <math.h>

#define B_    2
#define L_    4096
#define H_    8
#define E_    64
#define VTSTR 136        // u16 stride for Vt[e][parity*64 + rhat] (272B rows, 16B-aligned)
#define PSTR  72         // u16 stride for wave-private P rows (144B, 16B-aligned)

using frag8 = __attribute__((ext_vector_type(8))) short;  // 8 x bf16 (4 VGPRs)
using fl4   = __attribute__((ext_vector_type(4))) float;  // MFMA C/D / raw vec4 loads

__device__ __forceinline__ unsigned short f2bf(float f) {
    return __builtin_bit_cast(unsigned short, __float2bfloat16(f));
}
__device__ __forceinline__ frag8 pack8v(fl4 a, fl4 b) {
    frag8 r;
    r[0] = (short)f2bf(a.x); r[1] = (short)f2bf(a.y);
    r[2] = (short)f2bf(a.z); r[3] = (short)f2bf(a.w);
    r[4] = (short)f2bf(b.x); r[5] = (short)f2bf(b.y);
    r[6] = (short)f2bf(b.z); r[7] = (short)f2bf(b.w);
    return r;
}

__global__ __launch_bounds__(256, 4)
void lda_kernel(const float* __restrict__ Q, const float* __restrict__ K,
                const float* __restrict__ V, float* __restrict__ O) {
    __shared__ unsigned short Vt[E_ * VTSTR];        // 17408 B  (V transposed, parity-major)
    __shared__ unsigned short Pw[4 * 16 * PSTR];     //  9216 B  -> 26624 B, 4 blocks/CU

    const int tid  = threadIdx.x;
    const int lane = tid & 63;
    const int wave = tid >> 6;
    const int col  = lane & 15;
    const int quad = lane >> 4;
    const int p    = wave & 1;       // query parity this wave owns
    const int t    = wave >> 1;      // lhat tile (0 or 1)

    // XCD-aware remap: xcd = g&7 (HW round-robin) gets 8 consecutive l-tiles
    // x all 16 bh -> per-XCD K/V working set ~2.4 MB < 4 MB L2 (halo reuse).
    const int g   = blockIdx.x;
    const int xcd = g & 7;
    const int s   = g >> 3;          // 0..127
    const int bh  = s & 15;
    const int xt  = (xcd << 3) | (s >> 4);   // l-tile 0..63
    const int l0  = xt * 64;
    const int b   = bh >> 3;
    const int h   = bh & 7;

    const size_t base = ((size_t)(b * L_) * H_ + h) * E_;
    const int    rs   = H_ * E_;     // 512 floats per l-step

    // ---- 1) Q A-frags direct from global, nontemporal (single-use; keep L2 for K/V) ----
    const int lq = l0 + 2 * (16 * t + col) + p;
    frag8 aq[2];
    #pragma unroll
    for (int k = 0; k < 2; ++k) {
        const float* qp = Q + base + (size_t)lq * rs + k * 32 + quad * 8;
        fl4 qa = __builtin_nontemporal_load((const fl4*)qp);
        fl4 qb = __builtin_nontemporal_load((const fl4*)qp + 1);
        aq[k] = pack8v(qa, qb);
    }

    // ---- 2) scores: 3 rhat-tiles; K loads are the ONLY older vmem -> minimal waits ----
    fl4 S[3];
    #pragma unroll
    for (int c = 0; c < 3; ++c) {
        int rhat = 16 * (t + c) + col;
        int rg = l0 - 32 + 2 * rhat + p;
        rg = rg < 0 ? 0 : (rg > L_ - 1 ? L_ - 1 : rg);
        const float* kp = K + base + (size_t)rg * rs;
        fl4 acc = {0.f, 0.f, 0.f, 0.f};
        #pragma unroll
        for (int k = 0; k < 2; ++k) {
            frag8 bk = pack8v(*(const fl4*)(kp + k * 32 + quad * 8),
                              *(const fl4*)(kp + k * 32 + quad * 8 + 4));
            acc = __builtin_amdgcn_mfma_f32_16x16x32_bf16(aq[k], bk, acc, 0, 0, 0);
        }
        S[c] = acc;
    }

    // ---- 3) V loads issued now, held in regs; use deferred (latency overlapped) ----
    float va[32];
    #pragma unroll
    for (int i = 0; i < 8; ++i) {
        int gi  = wave * 8 + i;       // 0..31
        int pg  = gi >> 4;            // staged-row parity
        int rh0 = (gi & 15) * 4;
        #pragma unroll
        for (int j = 0; j < 4; ++j) {
            int rg = l0 - 32 + 2 * (rh0 + j) + pg;
            rg = rg < 0 ? 0 : (rg > L_ - 1 ? L_ - 1 : rg);
            va[i * 4 + j] = V[base + (size_t)rg * rs + lane];
        }
    }

    // ---- 4) unnormalized weights (no max-sub, no cross-lane): overlaps V latency ----
    float pw[3][4];
    #pragma unroll
    for (int c = 0; c < 3; ++c)
        #pragma unroll
        for (int reg = 0; reg < 4; ++reg)
            pw[c][reg] = exp2f(S[c][reg] * 0.18033688011112043f);  // 0.125*log2(e)

    // ---- 5) zero + scatter P into wave-private region (same-wave LDS order) ----
    const int pb = wave * 16 * PSTR;
    #pragma unroll
    for (int i = 0; i < 3; ++i) {
        int idx = lane + 64 * i;
        if (idx < 144) { uint4 z = {0u,0u,0u,0u}; *(uint4*)&Pw[pb + idx * 8] = z; }
    }
    #pragma unroll
    for (int reg = 0; reg < 4; ++reg) {
        int off = quad * 4 + reg;
        #pragma unroll
        for (int c = 0; c < 3; ++c) {
            int j = 16 * c + col - off;          // tap index 0..32
            if (j >= 0 && j <= 32)
                Pw[pb + off * PSTR + 16 * (t + c) + col] = f2bf(pw[c][reg]);
        }
    }

    // ---- 6) P A-frags + row sums via ones-MFMA (C-layout matches PV output) ----
    frag8 ap[2];
    #pragma unroll
    for (int k = 0; k < 2; ++k)
        ap[k] = *(const frag8*)&Pw[pb + col * PSTR + k * 32 + quad * 8];

    frag8 ones;
    #pragma unroll
    for (int i = 0; i < 8; ++i) ones[i] = (short)0x3F80;   // bf16 1.0
    fl4 sums = {0.f, 0.f, 0.f, 0.f};
    sums = __builtin_amdgcn_mfma_f32_16x16x32_bf16(ap[0], ones, sums, 0, 0, 0);
    sums = __builtin_amdgcn_mfma_f32_16x16x32_bf16(ap[1], ones, sums, 0, 0, 0);
    float inv[4];
    #pragma unroll
    for (int reg = 0; reg < 4; ++reg) inv[reg] = __builtin_amdgcn_rcpf(sums[reg]);

    // ---- 7) V pack + LDS transpose write (progressive vmcnt waits on V only) ----
    #pragma unroll
    for (int i = 0; i < 8; ++i) {
        int gi  = wave * 8 + i;
        int pg  = gi >> 4;
        int rh0 = (gi & 15) * 4;
        uint2 u;
        u.x = (unsigned)f2bf(va[i*4+0]) | ((unsigned)f2bf(va[i*4+1]) << 16);
        u.y = (unsigned)f2bf(va[i*4+2]) | ((unsigned)f2bf(va[i*4+3]) << 16);
        *(uint2*)&Vt[lane * VTSTR + pg * 64 + rh0] = u;   // e = lane
    }
    __syncthreads();   // the ONE barrier: Vt ready

    // ---- 8) PV MFMA: O[l][e] = (1/s_l) * sum_rhat P[lhat][rhat] * V[2rhat+p][e] ----
    #pragma unroll
    for (int nt = 0; nt < 4; ++nt) {
        fl4 c = {0.f, 0.f, 0.f, 0.f};
        #pragma unroll
        for (int k = 0; k < 2; ++k) {
            frag8 bv = *(const frag8*)&Vt[(nt * 16 + col) * VTSTR + p * 64 + k * 32 + quad * 8];
            c = __builtin_amdgcn_mfma_f32_16x16x32_bf16(ap[k], bv, c, 0, 0, 0);
        }
        #pragma unroll
        for (int reg = 0; reg < 4; ++reg) {
            int l = 2 * (16 * t + quad * 4 + reg) + p;
            __builtin_nontemporal_store(c[reg] * inv[reg],
                O + base + (size_t)(l0 + l) * rs + nt * 16 + col);
        }
    }
}

extern "C" void kernel_launch(void* const* d_in, const int* in_sizes, int n_in,
                              void* d_out, int out_size, void* d_ws, size_t ws_size,
                              hipStream_t stream) {
    const float* Q = (const float*)d_in[0];
    const float* K = (const float*)d_in[1];
    const float* V = (const float*)d_in[2];
    float* O = (float*)d_out;

    dim3 grid(L_ / 64 * B_ * H_);   // 1024, 1-D; XCD decomposition inside kernel
    dim3 block(256);
    lda_kernel<<<grid, block, 0, stream>>>(Q, K, V, O);
}

// Round 10
// 91.370 us; speedup vs baseline: 1.0830x; 1.0830x over previous
//
#include <hip/hip_runtime.h>
#include <hip/hip_bf16.h>
#include <math.h>

#define B_    2
#define L_    4096
#define H_    8
#define E_    64
#define VTSTR 136        // u16 stride for Vt[e][parity*64 + rhat] (272B rows, 16B-aligned)
#define PSTR  72         // u16 stride for wave-private P rows (144B, 16B-aligned)

using frag8 = __attribute__((ext_vector_type(8))) short;  // 8 x bf16 (4 VGPRs)
using fl4   = __attribute__((ext_vector_type(4))) float;  // MFMA C/D

__device__ __forceinline__ unsigned short f2bf(float f) {
    return __builtin_bit_cast(unsigned short, __float2bfloat16(f));
}
__device__ __forceinline__ frag8 pack8(float4 a, float4 b) {
    frag8 r;
    r[0] = (short)f2bf(a.x); r[1] = (short)f2bf(a.y);
    r[2] = (short)f2bf(a.z); r[3] = (short)f2bf(a.w);
    r[4] = (short)f2bf(b.x); r[5] = (short)f2bf(b.y);
    r[6] = (short)f2bf(b.z); r[7] = (short)f2bf(b.w);
    return r;
}

__global__ __launch_bounds__(256, 4)
void lda_kernel(const float* __restrict__ Q, const float* __restrict__ K,
                const float* __restrict__ V, float* __restrict__ O) {
    __shared__ unsigned short Vt[E_ * VTSTR];        // 17408 B  (V transposed, parity-major)
    __shared__ unsigned short Pw[4 * 16 * PSTR];     //  9216 B  -> 26624 B, 4 blocks/CU

    const int tid  = threadIdx.x;
    const int lane = tid & 63;
    const int wave = tid >> 6;
    const int col  = lane & 15;
    const int quad = lane >> 4;
    const int p    = wave & 1;       // query parity this wave owns
    const int t    = wave >> 1;      // lhat tile (0 or 1)

    // XCD-aware remap: xcd = g&7 (HW round-robin) gets 8 consecutive l-tiles
    // x all 16 bh -> per-XCD K/V working set ~2.4 MB < 4 MB L2 (halo reuse).
    const int g   = blockIdx.x;
    const int xcd = g & 7;
    const int s   = g >> 3;          // 0..127
    const int bh  = s & 15;
    const int xt  = (xcd << 3) | (s >> 4);   // l-tile 0..63
    const int l0  = xt * 64;
    const int b   = bh >> 3;
    const int h   = bh & 7;

    const size_t base = ((size_t)(b * L_) * H_ + h) * E_;
    const int    rs   = H_ * E_;     // 512 floats per l-step

    // ---- 1) Q A-frags direct from global (query l = 2*(16t+col)+p) ----
    const int lq = l0 + 2 * (16 * t + col) + p;
    frag8 aq[2];
    #pragma unroll
    for (int k = 0; k < 2; ++k) {
        const float* qp = Q + base + (size_t)lq * rs + k * 32 + quad * 8;
        aq[k] = pack8(*(const float4*)qp, *(const float4*)(qp + 4));
    }

    // ---- 2) scores: 3 rhat-tiles; K loads are the ONLY older vmem -> minimal waits ----
    fl4 S[3];
    #pragma unroll
    for (int c = 0; c < 3; ++c) {
        int rhat = 16 * (t + c) + col;
        int rg = l0 - 32 + 2 * rhat + p;
        rg = rg < 0 ? 0 : (rg > L_ - 1 ? L_ - 1 : rg);
        const float* kp = K + base + (size_t)rg * rs;
        fl4 acc = {0.f, 0.f, 0.f, 0.f};
        #pragma unroll
        for (int k = 0; k < 2; ++k) {
            frag8 bk = pack8(*(const float4*)(kp + k * 32 + quad * 8),
                             *(const float4*)(kp + k * 32 + quad * 8 + 4));
            acc = __builtin_amdgcn_mfma_f32_16x16x32_bf16(aq[k], bk, acc, 0, 0, 0);
        }
        S[c] = acc;
    }

    // ---- 3) V loads issued now, held in regs; use deferred (latency overlapped) ----
    float va[32];
    #pragma unroll
    for (int i = 0; i < 8; ++i) {
        int gi  = wave * 8 + i;       // 0..31
        int pg  = gi >> 4;            // staged-row parity
        int rh0 = (gi & 15) * 4;
        #pragma unroll
        for (int j = 0; j < 4; ++j) {
            int rg = l0 - 32 + 2 * (rh0 + j) + pg;
            rg = rg < 0 ? 0 : (rg > L_ - 1 ? L_ - 1 : rg);
            va[i * 4 + j] = V[base + (size_t)rg * rs + lane];
        }
    }

    // ---- 4) unnormalized weights (no max-sub, no cross-lane): overlaps V latency ----
    float pw[3][4];
    #pragma unroll
    for (int c = 0; c < 3; ++c)
        #pragma unroll
        for (int reg = 0; reg < 4; ++reg)
            pw[c][reg] = exp2f(S[c][reg] * 0.18033688011112043f);  // 0.125*log2(e)

    // ---- 5) zero + scatter P into wave-private region (same-wave LDS order) ----
    const int pb = wave * 16 * PSTR;
    #pragma unroll
    for (int i = 0; i < 3; ++i) {
        int idx = lane + 64 * i;
        if (idx < 144) { uint4 z = {0u,0u,0u,0u}; *(uint4*)&Pw[pb + idx * 8] = z; }
    }
    #pragma unroll
    for (int reg = 0; reg < 4; ++reg) {
        int off = quad * 4 + reg;
        #pragma unroll
        for (int c = 0; c < 3; ++c) {
            int j = 16 * c + col - off;          // tap index 0..32
            if (j >= 0 && j <= 32)
                Pw[pb + off * PSTR + 16 * (t + c) + col] = f2bf(pw[c][reg]);
        }
    }

    // ---- 6) P A-frags + row sums via ones-MFMA (C-layout matches PV output) ----
    frag8 ap[2];
    #pragma unroll
    for (int k = 0; k < 2; ++k)
        ap[k] = *(const frag8*)&Pw[pb + col * PSTR + k * 32 + quad * 8];

    frag8 ones;
    #pragma unroll
    for (int i = 0; i < 8; ++i) ones[i] = (short)0x3F80;   // bf16 1.0
    fl4 sums = {0.f, 0.f, 0.f, 0.f};
    sums = __builtin_amdgcn_mfma_f32_16x16x32_bf16(ap[0], ones, sums, 0, 0, 0);
    sums = __builtin_amdgcn_mfma_f32_16x16x32_bf16(ap[1], ones, sums, 0, 0, 0);
    float inv[4];
    #pragma unroll
    for (int reg = 0; reg < 4; ++reg) inv[reg] = __builtin_amdgcn_rcpf(sums[reg]);

    // ---- 7) V pack + LDS transpose write (progressive vmcnt waits on V only) ----
    #pragma unroll
    for (int i = 0; i < 8; ++i) {
        int gi  = wave * 8 + i;
        int pg  = gi >> 4;
        int rh0 = (gi & 15) * 4;
        uint2 u;
        u.x = (unsigned)f2bf(va[i*4+0]) | ((unsigned)f2bf(va[i*4+1]) << 16);
        u.y = (unsigned)f2bf(va[i*4+2]) | ((unsigned)f2bf(va[i*4+3]) << 16);
        *(uint2*)&Vt[lane * VTSTR + pg * 64 + rh0] = u;   // e = lane
    }
    __syncthreads();   // the ONE barrier: Vt ready

    // ---- 8) PV MFMA: O[l][e] = (1/s_l) * sum_rhat P[lhat][rhat] * V[2rhat+p][e] ----
    #pragma unroll
    for (int nt = 0; nt < 4; ++nt) {
        fl4 c = {0.f, 0.f, 0.f, 0.f};
        #pragma unroll
        for (int k = 0; k < 2; ++k) {
            frag8 bv = *(const frag8*)&Vt[(nt * 16 + col) * VTSTR + p * 64 + k * 32 + quad * 8];
            c = __builtin_amdgcn_mfma_f32_16x16x32_bf16(ap[k], bv, c, 0, 0, 0);
        }
        #pragma unroll
        for (int reg = 0; reg < 4; ++reg) {
            int l = 2 * (16 * t + quad * 4 + reg) + p;
            __builtin_nontemporal_store(c[reg] * inv[reg],
                O + base + (size_t)(l0 + l) * rs + nt * 16 + col);
        }
    }
}

extern "C" void kernel_launch(void* const* d_in, const int* in_sizes, int n_in,
                              void* d_out, int out_size, void* d_ws, size_t ws_size,
                              hipStream_t stream) {
    const float* Q = (const float*)d_in[0];
    const float* K = (const float*)d_in[1];
    const float* V = (const float*)d_in[2];
    float* O = (float*)d_out;

    dim3 grid(L_ / 64 * B_ * H_);   // 1024, 1-D; XCD decomposition inside kernel
    dim3 block(256);
    lda_kernel<<<grid, block, 0, stream>>>(Q, K, V, O);
}